// Round 3
// baseline (121.508 us; speedup 1.0000x reference)
//
#include <hip/hip_runtime.h>

typedef __bf16 bf16_t;
typedef __bf16 bf16x8 __attribute__((ext_vector_type(8)));
typedef __bf16 bf16x4 __attribute__((ext_vector_type(4)));
typedef float  f32x4  __attribute__((ext_vector_type(4)));

static constexpr int B_   = 2;
static constexpr int H_   = 48;
static constexpr int W_   = 48;
static constexpr int C_   = 512;
static constexpr int NH_  = 8;
static constexpr int HD_  = 64;
static constexpr int KW_  = 7;
static constexpr int ROWS_ = B_ * H_ * W_;    // 4608
static constexpr int QKVN_ = 3 * C_;          // 1536

// async global->LDS, 16B per lane; LDS dest = wave-uniform base + lane*16
#define GLDS16(g, l) __builtin_amdgcn_global_load_lds(                       \
    (const __attribute__((address_space(1))) void*)(g),                      \
    (__attribute__((address_space(3))) void*)(l), 16, 0, 0)

// C[m][n] = (sum_k A[m][k]*Wt[n][k] + bias[n]) * (n < scale_nlim ? scale : 1)
// Operands may be fp32 (converted to bf16 in-register during staging; kills
// the separate convert kernel + its dispatch gap) or bf16 (async global_load_lds).
// Single-buffered m97-style loop (best measured config, R1 = 105.9 us).
template<int BM, int BN, int WMT, int WNT, int KTILE,
         typename AT, typename BT, typename OutT>
__global__ __launch_bounds__(256)
void gemm_bt(const AT* __restrict__ A, const BT* __restrict__ Wt,
             const float* __restrict__ bias, OutT* __restrict__ C,
             int M, int N, int K, float scale, int scale_nlim)
{
    constexpr int WCOLS = BN / (WNT * 16);
    constexpr int CPR   = KTILE / 8;       // 16B bf16 chunks per row
    constexpr int RPI   = 64 / CPR;        // rows per staging instr
    constexpr int KSN   = KTILE / 32;      // mfma k-steps per tile
    __shared__ bf16_t Al[BM * KTILE];
    __shared__ bf16_t Bl[BN * KTILE];

    const int tid  = threadIdx.x;
    const int wave = tid >> 6;
    const int lane = tid & 63;

    // XCD-aware chunked swizzle (nwg % 8 == 0 for every launch below)
    const int gx  = gridDim.x;
    const int nwg = gx * gridDim.y;
    int lin = blockIdx.y * gx + blockIdx.x;
    if ((nwg & 7) == 0) lin = (lin & 7) * (nwg >> 3) + (lin >> 3);
    const int bm = (lin / gx) * BM;
    const int bn = (lin % gx) * BN;

    const int wm = (wave / WCOLS) * (WMT * 16);
    const int wn = (wave % WCOLS) * (WNT * 16);
    const int n15 = lane & 15, q4 = lane >> 4, x7 = lane & 7;
    const int srow = lane / CPR;
    const int schunk = lane % CPR;

    f32x4 acc[WMT][WNT] = {};

    for (int k0 = 0; k0 < K; k0 += KTILE) {
        __syncthreads();
        #pragma unroll
        for (int i = wave; i < BM / RPI; i += 4) {
            const int row = i * RPI + srow;
            const int cg = (schunk & ~7) | ((schunk & 7) ^ (row & 7));
            if constexpr (sizeof(AT) == 2) {
                GLDS16(A + (size_t)(bm + row) * K + k0 + cg * 8, Al + i * 512);
            } else {
                const float* s = (const float*)A + (size_t)(bm + row) * K + k0 + cg * 8;
                const float4 f0 = *reinterpret_cast<const float4*>(s);
                const float4 f1 = *reinterpret_cast<const float4*>(s + 4);
                bf16x8 o;
                o[0] = (bf16_t)f0.x; o[1] = (bf16_t)f0.y;
                o[2] = (bf16_t)f0.z; o[3] = (bf16_t)f0.w;
                o[4] = (bf16_t)f1.x; o[5] = (bf16_t)f1.y;
                o[6] = (bf16_t)f1.z; o[7] = (bf16_t)f1.w;
                *reinterpret_cast<bf16x8*>(Al + i * 512 + lane * 8) = o;
            }
        }
        #pragma unroll
        for (int i = wave; i < BN / RPI; i += 4) {
            const int row = i * RPI + srow;
            const int cg = (schunk & ~7) | ((schunk & 7) ^ (row & 7));
            if constexpr (sizeof(BT) == 2) {
                GLDS16(Wt + (size_t)(bn + row) * K + k0 + cg * 8, Bl + i * 512);
            } else {
                const float* s = (const float*)Wt + (size_t)(bn + row) * K + k0 + cg * 8;
                const float4 f0 = *reinterpret_cast<const float4*>(s);
                const float4 f1 = *reinterpret_cast<const float4*>(s + 4);
                bf16x8 o;
                o[0] = (bf16_t)f0.x; o[1] = (bf16_t)f0.y;
                o[2] = (bf16_t)f0.z; o[3] = (bf16_t)f0.w;
                o[4] = (bf16_t)f1.x; o[5] = (bf16_t)f1.y;
                o[6] = (bf16_t)f1.z; o[7] = (bf16_t)f1.w;
                *reinterpret_cast<bf16x8*>(Bl + i * 512 + lane * 8) = o;
            }
        }
        __syncthreads();

        #pragma unroll
        for (int ks = 0; ks < KSN; ++ks) {
            const int g = ks * 4 + q4;
            const int cl = (g & ~7) | ((g & 7) ^ x7);
            bf16x8 a[WMT], b[WNT];
            #pragma unroll
            for (int it = 0; it < WMT; ++it)
                a[it] = *reinterpret_cast<const bf16x8*>(
                    Al + (wm + it * 16 + n15) * KTILE + cl * 8);
            #pragma unroll
            for (int jt = 0; jt < WNT; ++jt)
                b[jt] = *reinterpret_cast<const bf16x8*>(
                    Bl + (wn + jt * 16 + n15) * KTILE + cl * 8);
            #pragma unroll
            for (int it = 0; it < WMT; ++it)
                #pragma unroll
                for (int jt = 0; jt < WNT; ++jt)
                    acc[it][jt] = __builtin_amdgcn_mfma_f32_16x16x32_bf16(
                        a[it], b[jt], acc[it][jt], 0, 0, 0);
        }
    }

    #pragma unroll
    for (int jt = 0; jt < WNT; ++jt) {
        const int col = bn + wn + jt * 16 + n15;
        const float bv = bias[col];
        const float sc = (col < scale_nlim) ? scale : 1.0f;
        #pragma unroll
        for (int it = 0; it < WMT; ++it) {
            const int row0 = bm + wm + it * 16 + q4 * 4;
            #pragma unroll
            for (int r = 0; r < 4; ++r)
                C[(size_t)(row0 + r) * N + col] = (OutT)((acc[it][jt][r] + bv) * sc);
        }
    }
}

// ---------------- MFMA neighborhood attention ----------------
// One block per (b, 8x8 pixel tile, head). 256 threads = 4 waves.
// Union window 14x14, 16-aligned k-index = wr*16+wc (wc 14,15 = clamp-dup
// pads, masked to P=0). Only K is LDS-staged (4x reuse across waves);
// V has ZERO intra-block reuse per element -> A-fragments are gathered
// straight from global (qkvb is L2/L3-resident), software-pipelined under
// the PV MFMAs.
static constexpr int WROW = 224;   // staged K rows = 14 tiles * 16
static constexpr int PST  = 232;   // P row stride (224+8, b128-aligned,
                                   // bank-step 20 -> 2 lanes/bank = free)
static constexpr int R1B  = 64 * PST * 2;    // 29696: P region (Kl aliases)

__global__ __launch_bounds__(256)
void attn_mfma_kernel(const bf16_t* __restrict__ qkv, bf16_t* __restrict__ attn_out)
{
    // XCD chunked swizzle: 576 % 8 == 0
    int bid = blockIdx.x;
    bid = (bid & 7) * ((int)gridDim.x >> 3) + (bid >> 3);
    const int h  = bid & 7;   bid >>= 3;
    const int tj = bid % 6;   bid /= 6;
    const int ti = bid % 6;   bid /= 6;
    const int b  = bid;

    const int tid = threadIdx.x;
    const int wave = tid >> 6;
    const int lane = tid & 63;
    const int n15 = lane & 15, q4 = lane >> 4, x7 = lane & 7;

    const int gi0 = ti * 8, gj0 = tj * 8;
    const int si0 = min(max(gi0 - 3, 0), H_ - 14);
    const int sj0 = min(max(gj0 - 3, 0), W_ - 14);

    __shared__ char smem[R1B];
    bf16_t* Kl = (bf16_t*)smem;            // [224][64] swizzled (first 28672 B)
    bf16_t* P  = (bf16_t*)smem;            // [64][232], aliases Kl

    // ---- stage K via async DMA ----
    for (int i = wave; i < WROW / 8; i += 4) {
        const int row = i * 8 + (lane >> 3);
        const int wr = row >> 4;
        const int wc = min(row & 15, 13);              // clamp-dup pad cols
        const int gp = (b * H_ + si0 + wr) * W_ + sj0 + wc;
        const bf16_t* gbase = qkv + (size_t)gp * QKVN_ + h * HD_;
        const int cgk = (lane & 7) ^ (row & 7);
        GLDS16(gbase + C_ + cgk * 8, Kl + i * 512);
    }

    // ---- Q fragments straight from global ----
    const int pixq = wave * 16 + n15;
    const int gpq = (b * H_ + gi0 + (pixq >> 3)) * W_ + gj0 + (pixq & 7);
    bf16x8 aq[2];
    #pragma unroll
    for (int ks = 0; ks < 2; ++ks)
        aq[ks] = *reinterpret_cast<const bf16x8*>(
            qkv + (size_t)gpq * QKVN_ + h * HD_ + ks * 32 + q4 * 8);

    __syncthreads();   // drain GLDS

    // ---- S = Q.K^T : 14 n-tiles x 2 k-steps ----
    f32x4 S[14] = {};
    #pragma unroll
    for (int j = 0; j < 14; ++j) {
        #pragma unroll
        for (int ks = 0; ks < 2; ++ks) {
            const int cl = (ks * 4 + q4) ^ x7;
            const bf16x8 bk = *reinterpret_cast<const bf16x8*>(
                Kl + (j * 16 + n15) * 64 + cl * 8);
            S[j] = __builtin_amdgcn_mfma_f32_16x16x32_bf16(aq[ks], bk, S[j], 0, 0, 0);
        }
    }

    // ---- V gather geometry (direct from global; per-lane column d) ----
    // av[u] = V[w = ks*32 + q4*8 + u][d = wave*16 + n15]
    const int clampu = (q4 & 1) ? 5 : 7;
    const bf16_t* vbase = qkv
        + (size_t)((b * H_ + si0 + (q4 >> 1)) * W_ + sj0 + (q4 & 1) * 8) * QKVN_
        + 2 * C_ + h * HD_ + (wave * 16 + n15);

    // prefetch ks=0 fragments now; latency hides under softmax
    bf16x8 avn;
    #pragma unroll
    for (int u = 0; u < 8; ++u)
        avn[u] = vbase[(size_t)min(u, clampu) * QKVN_];

    // ---- mask: tile j = window row, n15 = window col ----
    int ri[4], cj[4];
    #pragma unroll
    for (int r = 0; r < 4; ++r) {
        const int pix = wave * 16 + q4 * 4 + r;
        const int gi = gi0 + (pix >> 3), gj = gj0 + (pix & 7);
        ri[r] = min(max(gi - 3, 0), H_ - KW_) - si0;
        cj[r] = min(max(gj - 3, 0), W_ - KW_) - sj0;
    }
    #pragma unroll
    for (int j = 0; j < 14; ++j)
        #pragma unroll
        for (int r = 0; r < 4; ++r) {
            const bool valid = ((unsigned)(j - ri[r]) < 7u) &&
                               ((unsigned)(n15 - cj[r]) < 7u);
            S[j][r] = valid ? S[j][r] : -1e30f;
        }

    // ---- softmax, NO max pass (|logit| bounded ~2; expf(-1e30) = 0) ----
    #pragma unroll
    for (int j = 0; j < 14; ++j)
        #pragma unroll
        for (int r = 0; r < 4; ++r)
            S[j][r] = __expf(S[j][r]);
    float rinv[4];
    #pragma unroll
    for (int r = 0; r < 4; ++r) {
        float s = S[0][r];
        #pragma unroll
        for (int j = 1; j < 14; ++j) s += S[j][r];
        #pragma unroll
        for (int off = 1; off < 16; off <<= 1) s += __shfl_xor(s, off);
        rinv[r] = 1.0f / s;
    }

    __syncthreads();   // all waves done reading Kl -> overwrite with P

    // ---- write P (normalized probs; masked slots exactly 0) ----
    #pragma unroll
    for (int j = 0; j < 14; ++j)
        #pragma unroll
        for (int r = 0; r < 4; ++r)
            P[(wave * 16 + q4 * 4 + r) * PST + j * 16 + n15] =
                (bf16_t)(S[j][r] * rinv[r]);

    __syncthreads();

    // ---- O^T = V^T.P^T : A-frag streamed from global, double-buffered ----
    f32x4 O[4] = {};
    #pragma unroll
    for (int ks = 0; ks < 7; ++ks) {
        const bf16x8 av = avn;
        if (ks < 6) {
            const bf16_t* vb = vbase + (size_t)(ks + 1) * 2 * W_ * QKVN_;
            #pragma unroll
            for (int u = 0; u < 8; ++u)
                avn[u] = vb[(size_t)min(u, clampu) * QKVN_];
        }
        #pragma unroll
        for (int j2 = 0; j2 < 4; ++j2) {
            const bf16x8 bp = *reinterpret_cast<const bf16x8*>(
                P + (j2 * 16 + n15) * PST + ks * 32 + q4 * 8);
            O[j2] = __builtin_amdgcn_mfma_f32_16x16x32_bf16(av, bp, O[j2], 0, 0, 0);
        }
    }

    // ---- epilogue: D[m=d][n=pix], already normalized ----
    #pragma unroll
    for (int j2 = 0; j2 < 4; ++j2) {
        const int pix = j2 * 16 + n15;
        const int grow = (b * H_ + gi0 + (pix >> 3)) * W_ + gj0 + (pix & 7);
        const int d0 = wave * 16 + q4 * 4;
        bf16x4 o;
        #pragma unroll
        for (int r = 0; r < 4; ++r) o[r] = (bf16_t)(O[j2][r]);
        *reinterpret_cast<bf16x4*>(attn_out + (size_t)grow * C_ + h * HD_ + d0) = o;
    }
}

extern "C" void kernel_launch(void* const* d_in, const int* in_sizes, int n_in,
                              void* d_out, int out_size, void* d_ws, size_t ws_size,
                              hipStream_t stream)
{
    const float* x      = (const float*)d_in[0];
    const float* qkv_w  = (const float*)d_in[1];
    const float* qkv_b  = (const float*)d_in[2];
    const float* proj_w = (const float*)d_in[3];
    const float* proj_b = (const float*)d_in[4];
    float* out = (float*)d_out;

    char* w = (char*)d_ws;
    bf16_t* qkvb  = (bf16_t*)w;  w += (size_t)ROWS_ * QKVN_ * 2;
    bf16_t* attnb = (bf16_t*)w;

    // 1) QKV = x @ qkv_w.T + qkv_b ; q-part scaled by 0.125.
    //    fp32 operands converted in-register during staging (no convert pass).
    //    128x128 tile -> 12x36 = 432 blocks
    gemm_bt<128, 128, 4, 4, 64, float, float, bf16_t>
        <<<dim3(QKVN_ / 128, ROWS_ / 128), 256, 0, stream>>>(
        x, qkv_w, qkv_b, qkvb, ROWS_, QKVN_, C_, 0.125f, C_);

    // 2) neighborhood attention (MFMA), 576 blocks
    attn_mfma_kernel<<<dim3(B_ * 6 * 6 * NH_), 256, 0, stream>>>(qkvb, attnb);

    // 3) out = attn @ proj_w.T + proj_b.  A bf16 via GLDS, B fp32 reg-staged.
    //    64x64, KTILE=128 -> 8x72 = 576 blocks
    gemm_bt<64, 64, 2, 2, 128, bf16_t, float, float>
        <<<dim3(C_ / 64, ROWS_ / 64), 256, 0, stream>>>(
        attnb, proj_w, proj_b, out, ROWS_, C_, C_, 1.0f, 0);
}

// Round 4
// 107.629 us; speedup vs baseline: 1.1290x; 1.1290x over previous
//
#include <hip/hip_runtime.h>

typedef __bf16 bf16_t;
typedef __bf16 bf16x8 __attribute__((ext_vector_type(8)));
typedef __bf16 bf16x4 __attribute__((ext_vector_type(4)));
typedef float  f32x4  __attribute__((ext_vector_type(4)));

static constexpr int B_   = 2;
static constexpr int H_   = 48;
static constexpr int W_   = 48;
static constexpr int C_   = 512;
static constexpr int NH_  = 8;
static constexpr int HD_  = 64;
static constexpr int KW_  = 7;
static constexpr int ROWS_ = B_ * H_ * W_;    // 4608
static constexpr int QKVN_ = 3 * C_;          // 1536

// async global->LDS, 16B per lane; LDS dest = wave-uniform base + lane*16
#define GLDS16(g, l) __builtin_amdgcn_global_load_lds(                       \
    (const __attribute__((address_space(1))) void*)(g),                      \
    (__attribute__((address_space(3))) void*)(l), 16, 0, 0)

// C[m][n] = (sum_k A[m][k]*Wt[n][k] + bias[n]) * (n < scale_nlim ? scale : 1)
// fp32 operands are converted to bf16 in-register during staging (kills the
// separate convert kernel). CRITICAL: staging is two-phase — ALL global loads
// issued first into registers (static indices), then cvt+ds_write — otherwise
// the compiler serializes load->wait->write chains (R3: 84 VGPR, 42 us).
template<int BM, int BN, int WMT, int WNT, int KTILE,
         typename AT, typename BT, typename OutT>
__global__ __launch_bounds__(256)
void gemm_bt(const AT* __restrict__ A, const BT* __restrict__ Wt,
             const float* __restrict__ bias, OutT* __restrict__ C,
             int M, int N, int K, float scale, int scale_nlim)
{
    constexpr int WCOLS = BN / (WNT * 16);
    constexpr int CPR   = KTILE / 8;       // 16B bf16 chunks per row
    constexpr int RPI   = 64 / CPR;        // rows per staging instr
    constexpr int KSN   = KTILE / 32;      // mfma k-steps per tile
    constexpr int AIT   = (BM / RPI) / 4;  // staging iters per wave (A)
    constexpr int BIT   = (BN / RPI) / 4;  // staging iters per wave (B)
    __shared__ bf16_t Al[BM * KTILE];
    __shared__ bf16_t Bl[BN * KTILE];

    const int tid  = threadIdx.x;
    const int wave = tid >> 6;
    const int lane = tid & 63;

    // XCD-aware chunked swizzle (nwg % 8 == 0 for every launch below)
    const int gx  = gridDim.x;
    const int nwg = gx * gridDim.y;
    int lin = blockIdx.y * gx + blockIdx.x;
    if ((nwg & 7) == 0) lin = (lin & 7) * (nwg >> 3) + (lin >> 3);
    const int bm = (lin / gx) * BM;
    const int bn = (lin % gx) * BN;

    const int wm = (wave / WCOLS) * (WMT * 16);
    const int wn = (wave % WCOLS) * (WNT * 16);
    const int n15 = lane & 15, q4 = lane >> 4, x7 = lane & 7;
    const int srow = lane / CPR;
    const int schunk = lane % CPR;

    f32x4 acc[WMT][WNT] = {};

    for (int k0 = 0; k0 < K; k0 += KTILE) {
        __syncthreads();

        // ---- phase 1: issue ALL staging loads (nothing depends on them yet)
        float4 fa[AIT][2], fb[BIT][2];
        #pragma unroll
        for (int ii = 0; ii < AIT; ++ii) {
            const int row = (ii * 4 + wave) * RPI + srow;
            const int cg = (schunk & ~7) | ((schunk & 7) ^ (row & 7));
            if constexpr (sizeof(AT) == 2) {
                GLDS16(A + (size_t)(bm + row) * K + k0 + cg * 8,
                       Al + (ii * 4 + wave) * 512);
            } else {
                const float* s = (const float*)A + (size_t)(bm + row) * K + k0 + cg * 8;
                fa[ii][0] = *reinterpret_cast<const float4*>(s);
                fa[ii][1] = *reinterpret_cast<const float4*>(s + 4);
            }
        }
        #pragma unroll
        for (int ii = 0; ii < BIT; ++ii) {
            const int row = (ii * 4 + wave) * RPI + srow;
            const int cg = (schunk & ~7) | ((schunk & 7) ^ (row & 7));
            if constexpr (sizeof(BT) == 2) {
                GLDS16(Wt + (size_t)(bn + row) * K + k0 + cg * 8,
                       Bl + (ii * 4 + wave) * 512);
            } else {
                const float* s = (const float*)Wt + (size_t)(bn + row) * K + k0 + cg * 8;
                fb[ii][0] = *reinterpret_cast<const float4*>(s);
                fb[ii][1] = *reinterpret_cast<const float4*>(s + 4);
            }
        }

        // ---- phase 2: convert + LDS write (consumes the in-flight loads)
        if constexpr (sizeof(AT) == 4) {
            #pragma unroll
            for (int ii = 0; ii < AIT; ++ii) {
                bf16x8 o;
                o[0] = (bf16_t)fa[ii][0].x; o[1] = (bf16_t)fa[ii][0].y;
                o[2] = (bf16_t)fa[ii][0].z; o[3] = (bf16_t)fa[ii][0].w;
                o[4] = (bf16_t)fa[ii][1].x; o[5] = (bf16_t)fa[ii][1].y;
                o[6] = (bf16_t)fa[ii][1].z; o[7] = (bf16_t)fa[ii][1].w;
                *reinterpret_cast<bf16x8*>(Al + (ii * 4 + wave) * 512 + lane * 8) = o;
            }
        }
        if constexpr (sizeof(BT) == 4) {
            #pragma unroll
            for (int ii = 0; ii < BIT; ++ii) {
                bf16x8 o;
                o[0] = (bf16_t)fb[ii][0].x; o[1] = (bf16_t)fb[ii][0].y;
                o[2] = (bf16_t)fb[ii][0].z; o[3] = (bf16_t)fb[ii][0].w;
                o[4] = (bf16_t)fb[ii][1].x; o[5] = (bf16_t)fb[ii][1].y;
                o[6] = (bf16_t)fb[ii][1].z; o[7] = (bf16_t)fb[ii][1].w;
                *reinterpret_cast<bf16x8*>(Bl + (ii * 4 + wave) * 512 + lane * 8) = o;
            }
        }
        __syncthreads();

        #pragma unroll
        for (int ks = 0; ks < KSN; ++ks) {
            const int g = ks * 4 + q4;
            const int cl = (g & ~7) | ((g & 7) ^ x7);
            bf16x8 a[WMT], b[WNT];
            #pragma unroll
            for (int it = 0; it < WMT; ++it)
                a[it] = *reinterpret_cast<const bf16x8*>(
                    Al + (wm + it * 16 + n15) * KTILE + cl * 8);
            #pragma unroll
            for (int jt = 0; jt < WNT; ++jt)
                b[jt] = *reinterpret_cast<const bf16x8*>(
                    Bl + (wn + jt * 16 + n15) * KTILE + cl * 8);
            #pragma unroll
            for (int it = 0; it < WMT; ++it)
                #pragma unroll
                for (int jt = 0; jt < WNT; ++jt)
                    acc[it][jt] = __builtin_amdgcn_mfma_f32_16x16x32_bf16(
                        a[it], b[jt], acc[it][jt], 0, 0, 0);
        }
    }

    #pragma unroll
    for (int jt = 0; jt < WNT; ++jt) {
        const int col = bn + wn + jt * 16 + n15;
        const float bv = bias[col];
        const float sc = (col < scale_nlim) ? scale : 1.0f;
        #pragma unroll
        for (int it = 0; it < WMT; ++it) {
            const int row0 = bm + wm + it * 16 + q4 * 4;
            #pragma unroll
            for (int r = 0; r < 4; ++r)
                C[(size_t)(row0 + r) * N + col] = (OutT)((acc[it][jt][r] + bv) * sc);
        }
    }
}

// ---------------- MFMA neighborhood attention ----------------
// One block per (b, 8x8 pixel tile, head). 256 threads = 4 waves.
// Union window 14x14, 16-aligned k-index = wr*16+wc (wc 14,15 = clamp-dup
// pads, masked to P=0). Only K is LDS-staged (4x reuse across waves);
// V has ZERO intra-block reuse per element -> A-fragments are gathered
// straight from global (qkvb is L2/L3-resident), software-pipelined under
// the PV MFMAs.
static constexpr int WROW = 224;   // staged K rows = 14 tiles * 16
static constexpr int PST  = 232;   // P row stride (224+8, b128-aligned,
                                   // bank-step 20 -> 2 lanes/bank = free)
static constexpr int R1B  = 64 * PST * 2;    // 29696: P region (Kl aliases)

__global__ __launch_bounds__(256)
void attn_mfma_kernel(const bf16_t* __restrict__ qkv, bf16_t* __restrict__ attn_out)
{
    // XCD chunked swizzle: 576 % 8 == 0
    int bid = blockIdx.x;
    bid = (bid & 7) * ((int)gridDim.x >> 3) + (bid >> 3);
    const int h  = bid & 7;   bid >>= 3;
    const int tj = bid % 6;   bid /= 6;
    const int ti = bid % 6;   bid /= 6;
    const int b  = bid;

    const int tid = threadIdx.x;
    const int wave = tid >> 6;
    const int lane = tid & 63;
    const int n15 = lane & 15, q4 = lane >> 4, x7 = lane & 7;

    const int gi0 = ti * 8, gj0 = tj * 8;
    const int si0 = min(max(gi0 - 3, 0), H_ - 14);
    const int sj0 = min(max(gj0 - 3, 0), W_ - 14);

    __shared__ char smem[R1B];
    bf16_t* Kl = (bf16_t*)smem;            // [224][64] swizzled (first 28672 B)
    bf16_t* P  = (bf16_t*)smem;            // [64][232], aliases Kl

    // ---- stage K via async DMA ----
    for (int i = wave; i < WROW / 8; i += 4) {
        const int row = i * 8 + (lane >> 3);
        const int wr = row >> 4;
        const int wc = min(row & 15, 13);              // clamp-dup pad cols
        const int gp = (b * H_ + si0 + wr) * W_ + sj0 + wc;
        const bf16_t* gbase = qkv + (size_t)gp * QKVN_ + h * HD_;
        const int cgk = (lane & 7) ^ (row & 7);
        GLDS16(gbase + C_ + cgk * 8, Kl + i * 512);
    }

    // ---- Q fragments straight from global ----
    const int pixq = wave * 16 + n15;
    const int gpq = (b * H_ + gi0 + (pixq >> 3)) * W_ + gj0 + (pixq & 7);
    bf16x8 aq[2];
    #pragma unroll
    for (int ks = 0; ks < 2; ++ks)
        aq[ks] = *reinterpret_cast<const bf16x8*>(
            qkv + (size_t)gpq * QKVN_ + h * HD_ + ks * 32 + q4 * 8);

    __syncthreads();   // drain GLDS

    // ---- S = Q.K^T : 14 n-tiles x 2 k-steps ----
    f32x4 S[14] = {};
    #pragma unroll
    for (int j = 0; j < 14; ++j) {
        #pragma unroll
        for (int ks = 0; ks < 2; ++ks) {
            const int cl = (ks * 4 + q4) ^ x7;
            const bf16x8 bk = *reinterpret_cast<const bf16x8*>(
                Kl + (j * 16 + n15) * 64 + cl * 8);
            S[j] = __builtin_amdgcn_mfma_f32_16x16x32_bf16(aq[ks], bk, S[j], 0, 0, 0);
        }
    }

    // ---- V gather geometry (direct from global; per-lane column d) ----
    // av[u] = V[w = ks*32 + q4*8 + u][d = wave*16 + n15]
    const int clampu = (q4 & 1) ? 5 : 7;
    const bf16_t* vbase = qkv
        + (size_t)((b * H_ + si0 + (q4 >> 1)) * W_ + sj0 + (q4 & 1) * 8) * QKVN_
        + 2 * C_ + h * HD_ + (wave * 16 + n15);

    // prefetch ks=0 fragments now; latency hides under softmax
    bf16x8 avn;
    #pragma unroll
    for (int u = 0; u < 8; ++u)
        avn[u] = vbase[(size_t)min(u, clampu) * QKVN_];

    // ---- mask: tile j = window row, n15 = window col ----
    int ri[4], cj[4];
    #pragma unroll
    for (int r = 0; r < 4; ++r) {
        const int pix = wave * 16 + q4 * 4 + r;
        const int gi = gi0 + (pix >> 3), gj = gj0 + (pix & 7);
        ri[r] = min(max(gi - 3, 0), H_ - KW_) - si0;
        cj[r] = min(max(gj - 3, 0), W_ - KW_) - sj0;
    }
    #pragma unroll
    for (int j = 0; j < 14; ++j)
        #pragma unroll
        for (int r = 0; r < 4; ++r) {
            const bool valid = ((unsigned)(j - ri[r]) < 7u) &&
                               ((unsigned)(n15 - cj[r]) < 7u);
            S[j][r] = valid ? S[j][r] : -1e30f;
        }

    // ---- softmax, NO max pass (|logit| bounded ~2; expf(-1e30) = 0) ----
    #pragma unroll
    for (int j = 0; j < 14; ++j)
        #pragma unroll
        for (int r = 0; r < 4; ++r)
            S[j][r] = __expf(S[j][r]);
    float rinv[4];
    #pragma unroll
    for (int r = 0; r < 4; ++r) {
        float s = S[0][r];
        #pragma unroll
        for (int j = 1; j < 14; ++j) s += S[j][r];
        #pragma unroll
        for (int off = 1; off < 16; off <<= 1) s += __shfl_xor(s, off);
        rinv[r] = 1.0f / s;
    }

    __syncthreads();   // all waves done reading Kl -> overwrite with P

    // ---- write P (normalized probs; masked slots exactly 0) ----
    #pragma unroll
    for (int j = 0; j < 14; ++j)
        #pragma unroll
        for (int r = 0; r < 4; ++r)
            P[(wave * 16 + q4 * 4 + r) * PST + j * 16 + n15] =
                (bf16_t)(S[j][r] * rinv[r]);

    __syncthreads();

    // ---- O^T = V^T.P^T : A-frag streamed from global, double-buffered ----
    f32x4 O[4] = {};
    #pragma unroll
    for (int ks = 0; ks < 7; ++ks) {
        const bf16x8 av = avn;
        if (ks < 6) {
            const bf16_t* vb = vbase + (size_t)(ks + 1) * 2 * W_ * QKVN_;
            #pragma unroll
            for (int u = 0; u < 8; ++u)
                avn[u] = vb[(size_t)min(u, clampu) * QKVN_];
        }
        #pragma unroll
        for (int j2 = 0; j2 < 4; ++j2) {
            const bf16x8 bp = *reinterpret_cast<const bf16x8*>(
                P + (j2 * 16 + n15) * PST + ks * 32 + q4 * 8);
            O[j2] = __builtin_amdgcn_mfma_f32_16x16x32_bf16(av, bp, O[j2], 0, 0, 0);
        }
    }

    // ---- epilogue: D[m=d][n=pix], already normalized ----
    #pragma unroll
    for (int j2 = 0; j2 < 4; ++j2) {
        const int pix = j2 * 16 + n15;
        const int grow = (b * H_ + gi0 + (pix >> 3)) * W_ + gj0 + (pix & 7);
        const int d0 = wave * 16 + q4 * 4;
        bf16x4 o;
        #pragma unroll
        for (int r = 0; r < 4; ++r) o[r] = (bf16_t)(O[j2][r]);
        *reinterpret_cast<bf16x4*>(attn_out + (size_t)grow * C_ + h * HD_ + d0) = o;
    }
}

extern "C" void kernel_launch(void* const* d_in, const int* in_sizes, int n_in,
                              void* d_out, int out_size, void* d_ws, size_t ws_size,
                              hipStream_t stream)
{
    const float* x      = (const float*)d_in[0];
    const float* qkv_w  = (const float*)d_in[1];
    const float* qkv_b  = (const float*)d_in[2];
    const float* proj_w = (const float*)d_in[3];
    const float* proj_b = (const float*)d_in[4];
    float* out = (float*)d_out;

    char* w = (char*)d_ws;
    bf16_t* qkvb  = (bf16_t*)w;  w += (size_t)ROWS_ * QKVN_ * 2;
    bf16_t* attnb = (bf16_t*)w;

    // 1) QKV = x @ qkv_w.T + qkv_b ; q-part scaled by 0.125.
    //    fp32 operands converted in-register (two-phase staging).
    //    128x128 tile -> 12x36 = 432 blocks
    gemm_bt<128, 128, 4, 4, 64, float, float, bf16_t>
        <<<dim3(QKVN_ / 128, ROWS_ / 128), 256, 0, stream>>>(
        x, qkv_w, qkv_b, qkvb, ROWS_, QKVN_, C_, 0.125f, C_);

    // 2) neighborhood attention (MFMA), 576 blocks
    attn_mfma_kernel<<<dim3(B_ * 6 * 6 * NH_), 256, 0, stream>>>(qkvb, attnb);

    // 3) out = attn @ proj_w.T + proj_b.  A bf16 via GLDS, B fp32 reg-staged.
    //    64x64, KTILE=128 -> 8x72 = 576 blocks
    gemm_bt<64, 64, 2, 2, 128, bf16_t, float, float>
        <<<dim3(C_ / 64, ROWS_ / 64), 256, 0, stream>>>(
        attnb, proj_w, proj_b, out, ROWS_, C_, C_, 1.0f, 0);
}

// Round 6
// 106.785 us; speedup vs baseline: 1.1379x; 1.0079x over previous
//
#include <hip/hip_runtime.h>

typedef __bf16 bf16_t;
typedef __bf16 bf16x8 __attribute__((ext_vector_type(8)));
typedef __bf16 bf16x4 __attribute__((ext_vector_type(4)));
typedef float  f32x4  __attribute__((ext_vector_type(4)));

static constexpr int B_   = 2;
static constexpr int H_   = 48;
static constexpr int W_   = 48;
static constexpr int C_   = 512;
static constexpr int NH_  = 8;
static constexpr int HD_  = 64;
static constexpr int KW_  = 7;
static constexpr int ROWS_ = B_ * H_ * W_;    // 4608
static constexpr int QKVN_ = 3 * C_;          // 1536

// async global->LDS, 16B per lane; LDS dest = wave-uniform base + lane*16
#define GLDS16(g, l) __builtin_amdgcn_global_load_lds(                       \
    (const __attribute__((address_space(1))) void*)(g),                      \
    (__attribute__((address_space(3))) void*)(l), 16, 0, 0)

// C[m][n] = (sum_k A[m][k]*Wt[n][k] + bias[n]) * (n < scale_nlim ? scale : 1)
// T14 issue-early/write-late staging, single LDS buffer:
//   loadregs(t+1) -> compute(t) -> barrier -> writelds(t+1) -> barrier
// Load latency hides under compute instead of being exposed at the barrier
// (at ~2 blocks/CU there is no cross-wave overlap to hide it otherwise).
// fp32 operands are converted to bf16 in-register during the LDS write.
template<int BM, int BN, int WMT, int WNT, int KTILE,
         typename AT, typename BT, typename OutT>
__global__ __launch_bounds__(256)
void gemm_bt(const AT* __restrict__ A, const BT* __restrict__ Wt,
             const float* __restrict__ bias, OutT* __restrict__ C,
             int M, int N, int K, float scale, int scale_nlim)
{
    constexpr int WCOLS = BN / (WNT * 16);
    constexpr int CPR   = KTILE / 8;       // 16B bf16 chunks per row
    constexpr int RPI   = 64 / CPR;        // rows per staging instr
    constexpr int KSN   = KTILE / 32;      // mfma k-steps per tile
    constexpr int AIT   = (BM / RPI) / 4;  // staging iters per wave (A)
    constexpr int BIT   = (BN / RPI) / 4;  // staging iters per wave (B)
    __shared__ bf16_t Al[BM * KTILE];
    __shared__ bf16_t Bl[BN * KTILE];

    const int tid  = threadIdx.x;
    const int wave = tid >> 6;
    const int lane = tid & 63;

    // XCD-aware chunked swizzle (nwg % 8 == 0 for every launch below)
    const int gx  = gridDim.x;
    const int nwg = gx * gridDim.y;
    int lin = blockIdx.y * gx + blockIdx.x;
    if ((nwg & 7) == 0) lin = (lin & 7) * (nwg >> 3) + (lin >> 3);
    const int bm = (lin / gx) * BM;
    const int bn = (lin % gx) * BN;

    const int wm = (wave / WCOLS) * (WMT * 16);
    const int wn = (wave % WCOLS) * (WNT * 16);
    const int n15 = lane & 15, q4 = lane >> 4, x7 = lane & 7;
    const int srow = lane / CPR;
    const int schunk = lane % CPR;

    // staging registers (static-indexed, fully unrolled everywhere)
    float4 fa32[AIT][2]; bf16x8 fa16[AIT];
    float4 fb32[BIT][2]; bf16x8 fb16[BIT];

    auto loadregs = [&](int k0) {
        #pragma unroll
        for (int ii = 0; ii < AIT; ++ii) {
            const int row = (ii * 4 + wave) * RPI + srow;
            const int cg = (schunk & ~7) | ((schunk & 7) ^ (row & 7));
            const AT* s = A + (size_t)(bm + row) * K + k0 + cg * 8;
            if constexpr (sizeof(AT) == 2) {
                fa16[ii] = *reinterpret_cast<const bf16x8*>(s);
            } else {
                fa32[ii][0] = *reinterpret_cast<const float4*>(s);
                fa32[ii][1] = *reinterpret_cast<const float4*>(s + 4);
            }
        }
        #pragma unroll
        for (int ii = 0; ii < BIT; ++ii) {
            const int row = (ii * 4 + wave) * RPI + srow;
            const int cg = (schunk & ~7) | ((schunk & 7) ^ (row & 7));
            const BT* s = Wt + (size_t)(bn + row) * K + k0 + cg * 8;
            if constexpr (sizeof(BT) == 2) {
                fb16[ii] = *reinterpret_cast<const bf16x8*>(s);
            } else {
                fb32[ii][0] = *reinterpret_cast<const float4*>(s);
                fb32[ii][1] = *reinterpret_cast<const float4*>(s + 4);
            }
        }
    };

    auto writelds = [&]() {
        #pragma unroll
        for (int ii = 0; ii < AIT; ++ii) {
            bf16x8 o;
            if constexpr (sizeof(AT) == 2) {
                o = fa16[ii];
            } else {
                o[0] = (bf16_t)fa32[ii][0].x; o[1] = (bf16_t)fa32[ii][0].y;
                o[2] = (bf16_t)fa32[ii][0].z; o[3] = (bf16_t)fa32[ii][0].w;
                o[4] = (bf16_t)fa32[ii][1].x; o[5] = (bf16_t)fa32[ii][1].y;
                o[6] = (bf16_t)fa32[ii][1].z; o[7] = (bf16_t)fa32[ii][1].w;
            }
            *reinterpret_cast<bf16x8*>(Al + (ii * 4 + wave) * 512 + lane * 8) = o;
        }
        #pragma unroll
        for (int ii = 0; ii < BIT; ++ii) {
            bf16x8 o;
            if constexpr (sizeof(BT) == 2) {
                o = fb16[ii];
            } else {
                o[0] = (bf16_t)fb32[ii][0].x; o[1] = (bf16_t)fb32[ii][0].y;
                o[2] = (bf16_t)fb32[ii][0].z; o[3] = (bf16_t)fb32[ii][0].w;
                o[4] = (bf16_t)fb32[ii][1].x; o[5] = (bf16_t)fb32[ii][1].y;
                o[6] = (bf16_t)fb32[ii][1].z; o[7] = (bf16_t)fb32[ii][1].w;
            }
            *reinterpret_cast<bf16x8*>(Bl + (ii * 4 + wave) * 512 + lane * 8) = o;
        }
    };

    f32x4 acc[WMT][WNT] = {};

    // prologue: first tile staged (latency exposed once)
    loadregs(0);
    writelds();
    __syncthreads();

    const int nT = K / KTILE;
    for (int t = 0; t < nT; ++t) {
        // issue next tile's loads BEFORE compute; they fly under the MFMAs
        if (t + 1 < nT) loadregs((t + 1) * KTILE);

        #pragma unroll
        for (int ks = 0; ks < KSN; ++ks) {
            const int g = ks * 4 + q4;
            const int cl = (g & ~7) | ((g & 7) ^ x7);
            bf16x8 a[WMT], b[WNT];
            #pragma unroll
            for (int it = 0; it < WMT; ++it)
                a[it] = *reinterpret_cast<const bf16x8*>(
                    Al + (wm + it * 16 + n15) * KTILE + cl * 8);
            #pragma unroll
            for (int jt = 0; jt < WNT; ++jt)
                b[jt] = *reinterpret_cast<const bf16x8*>(
                    Bl + (wn + jt * 16 + n15) * KTILE + cl * 8);
            #pragma unroll
            for (int it = 0; it < WMT; ++it)
                #pragma unroll
                for (int jt = 0; jt < WNT; ++jt)
                    acc[it][jt] = __builtin_amdgcn_mfma_f32_16x16x32_bf16(
                        a[it], b[jt], acc[it][jt], 0, 0, 0);
        }
        __syncthreads();               // all waves done reading the buffer
        if (t + 1 < nT) {
            writelds();                // loads have returned during compute
            __syncthreads();
        }
    }

    #pragma unroll
    for (int jt = 0; jt < WNT; ++jt) {
        const int col = bn + wn + jt * 16 + n15;
        const float bv = bias[col];
        const float sc = (col < scale_nlim) ? scale : 1.0f;
        #pragma unroll
        for (int it = 0; it < WMT; ++it) {
            const int row0 = bm + wm + it * 16 + q4 * 4;
            #pragma unroll
            for (int r = 0; r < 4; ++r)
                C[(size_t)(row0 + r) * N + col] = (OutT)((acc[it][jt][r] + bv) * sc);
        }
    }
}

// ---------------- MFMA neighborhood attention ----------------
// One block per (b, 8x8 pixel tile, head). 256 threads = 4 waves.
// Union window 14x14, 16-aligned k-index = wr*16+wc (wc 14,15 = clamp-dup
// pads, masked to P=0). Only K is LDS-staged (4x reuse across waves);
// V has ZERO intra-block reuse per element -> A-fragments are gathered
// straight from global (qkvb is L2/L3-resident), software-pipelined under
// the PV MFMAs.
static constexpr int WROW = 224;   // staged K rows = 14 tiles * 16
static constexpr int PST  = 232;   // P row stride (224+8, b128-aligned,
                                   // bank-step 20 -> 2 lanes/bank = free)
static constexpr int R1B  = 64 * PST * 2;    // 29696: P region (Kl aliases)

__global__ __launch_bounds__(256)
void attn_mfma_kernel(const bf16_t* __restrict__ qkv, bf16_t* __restrict__ attn_out)
{
    // XCD chunked swizzle: 576 % 8 == 0
    int bid = blockIdx.x;
    bid = (bid & 7) * ((int)gridDim.x >> 3) + (bid >> 3);
    const int h  = bid & 7;   bid >>= 3;
    const int tj = bid % 6;   bid /= 6;
    const int ti = bid % 6;   bid /= 6;
    const int b  = bid;

    const int tid = threadIdx.x;
    const int wave = tid >> 6;
    const int lane = tid & 63;
    const int n15 = lane & 15, q4 = lane >> 4, x7 = lane & 7;

    const int gi0 = ti * 8, gj0 = tj * 8;
    const int si0 = min(max(gi0 - 3, 0), H_ - 14);
    const int sj0 = min(max(gj0 - 3, 0), W_ - 14);

    __shared__ char smem[R1B];
    bf16_t* Kl = (bf16_t*)smem;            // [224][64] swizzled (first 28672 B)
    bf16_t* P  = (bf16_t*)smem;            // [64][232], aliases Kl

    // ---- stage K via async DMA ----
    for (int i = wave; i < WROW / 8; i += 4) {
        const int row = i * 8 + (lane >> 3);
        const int wr = row >> 4;
        const int wc = min(row & 15, 13);              // clamp-dup pad cols
        const int gp = (b * H_ + si0 + wr) * W_ + sj0 + wc;
        const bf16_t* gbase = qkv + (size_t)gp * QKVN_ + h * HD_;
        const int cgk = (lane & 7) ^ (row & 7);
        GLDS16(gbase + C_ + cgk * 8, Kl + i * 512);
    }

    // ---- Q fragments straight from global ----
    const int pixq = wave * 16 + n15;
    const int gpq = (b * H_ + gi0 + (pixq >> 3)) * W_ + gj0 + (pixq & 7);
    bf16x8 aq[2];
    #pragma unroll
    for (int ks = 0; ks < 2; ++ks)
        aq[ks] = *reinterpret_cast<const bf16x8*>(
            qkv + (size_t)gpq * QKVN_ + h * HD_ + ks * 32 + q4 * 8);

    __syncthreads();   // drain GLDS

    // ---- S = Q.K^T : 14 n-tiles x 2 k-steps ----
    f32x4 S[14] = {};
    #pragma unroll
    for (int j = 0; j < 14; ++j) {
        #pragma unroll
        for (int ks = 0; ks < 2; ++ks) {
            const int cl = (ks * 4 + q4) ^ x7;
            const bf16x8 bk = *reinterpret_cast<const bf16x8*>(
                Kl + (j * 16 + n15) * 64 + cl * 8);
            S[j] = __builtin_amdgcn_mfma_f32_16x16x32_bf16(aq[ks], bk, S[j], 0, 0, 0);
        }
    }

    // ---- V gather geometry (direct from global; per-lane column d) ----
    // av[u] = V[w = ks*32 + q4*8 + u][d = wave*16 + n15]
    const int clampu = (q4 & 1) ? 5 : 7;
    const bf16_t* vbase = qkv
        + (size_t)((b * H_ + si0 + (q4 >> 1)) * W_ + sj0 + (q4 & 1) * 8) * QKVN_
        + 2 * C_ + h * HD_ + (wave * 16 + n15);

    // prefetch ks=0 fragments now; latency hides under softmax
    bf16x8 avn;
    #pragma unroll
    for (int u = 0; u < 8; ++u)
        avn[u] = vbase[(size_t)min(u, clampu) * QKVN_];

    // ---- mask: tile j = window row, n15 = window col ----
    int ri[4], cj[4];
    #pragma unroll
    for (int r = 0; r < 4; ++r) {
        const int pix = wave * 16 + q4 * 4 + r;
        const int gi = gi0 + (pix >> 3), gj = gj0 + (pix & 7);
        ri[r] = min(max(gi - 3, 0), H_ - KW_) - si0;
        cj[r] = min(max(gj - 3, 0), W_ - KW_) - sj0;
    }
    #pragma unroll
    for (int j = 0; j < 14; ++j)
        #pragma unroll
        for (int r = 0; r < 4; ++r) {
            const bool valid = ((unsigned)(j - ri[r]) < 7u) &&
                               ((unsigned)(n15 - cj[r]) < 7u);
            S[j][r] = valid ? S[j][r] : -1e30f;
        }

    // ---- softmax, NO max pass (|logit| bounded ~2; expf(-1e30) = 0) ----
    #pragma unroll
    for (int j = 0; j < 14; ++j)
        #pragma unroll
        for (int r = 0; r < 4; ++r)
            S[j][r] = __expf(S[j][r]);
    float rinv[4];
    #pragma unroll
    for (int r = 0; r < 4; ++r) {
        float s = S[0][r];
        #pragma unroll
        for (int j = 1; j < 14; ++j) s += S[j][r];
        #pragma unroll
        for (int off = 1; off < 16; off <<= 1) s += __shfl_xor(s, off);
        rinv[r] = 1.0f / s;
    }

    __syncthreads();   // all waves done reading Kl -> overwrite with P

    // ---- write P (normalized probs; masked slots exactly 0) ----
    #pragma unroll
    for (int j = 0; j < 14; ++j)
        #pragma unroll
        for (int r = 0; r < 4; ++r)
            P[(wave * 16 + q4 * 4 + r) * PST + j * 16 + n15] =
                (bf16_t)(S[j][r] * rinv[r]);

    __syncthreads();

    // ---- O^T = V^T.P^T : A-frag streamed from global, double-buffered ----
    f32x4 O[4] = {};
    #pragma unroll
    for (int ks = 0; ks < 7; ++ks) {
        const bf16x8 av = avn;
        if (ks < 6) {
            const bf16_t* vb = vbase + (size_t)(ks + 1) * 2 * W_ * QKVN_;
            #pragma unroll
            for (int u = 0; u < 8; ++u)
                avn[u] = vb[(size_t)min(u, clampu) * QKVN_];
        }
        #pragma unroll
        for (int j2 = 0; j2 < 4; ++j2) {
            const bf16x8 bp = *reinterpret_cast<const bf16x8*>(
                P + (j2 * 16 + n15) * PST + ks * 32 + q4 * 8);
            O[j2] = __builtin_amdgcn_mfma_f32_16x16x32_bf16(av, bp, O[j2], 0, 0, 0);
        }
    }

    // ---- epilogue: D[m=d][n=pix], already normalized ----
    #pragma unroll
    for (int j2 = 0; j2 < 4; ++j2) {
        const int pix = j2 * 16 + n15;
        const int grow = (b * H_ + gi0 + (pix >> 3)) * W_ + gj0 + (pix & 7);
        const int d0 = wave * 16 + q4 * 4;
        bf16x4 o;
        #pragma unroll
        for (int r = 0; r < 4; ++r) o[r] = (bf16_t)(O[j2][r]);
        *reinterpret_cast<bf16x4*>(attn_out + (size_t)grow * C_ + h * HD_ + d0) = o;
    }
}

extern "C" void kernel_launch(void* const* d_in, const int* in_sizes, int n_in,
                              void* d_out, int out_size, void* d_ws, size_t ws_size,
                              hipStream_t stream)
{
    const float* x      = (const float*)d_in[0];
    const float* qkv_w  = (const float*)d_in[1];
    const float* qkv_b  = (const float*)d_in[2];
    const float* proj_w = (const float*)d_in[3];
    const float* proj_b = (const float*)d_in[4];
    float* out = (float*)d_out;

    char* w = (char*)d_ws;
    bf16_t* qkvb  = (bf16_t*)w;  w += (size_t)ROWS_ * QKVN_ * 2;
    bf16_t* attnb = (bf16_t*)w;

    // 1) QKV = x @ qkv_w.T + qkv_b ; q-part scaled by 0.125.
    //    fp32 operands converted in-register; T14 pipelined staging.
    //    128x128 tile -> 12x36 = 432 blocks
    gemm_bt<128, 128, 4, 4, 64, float, float, bf16_t>
        <<<dim3(QKVN_ / 128, ROWS_ / 128), 256, 0, stream>>>(
        x, qkv_w, qkv_b, qkvb, ROWS_, QKVN_, C_, 0.125f, C_);

    // 2) neighborhood attention (MFMA), 576 blocks
    attn_mfma_kernel<<<dim3(B_ * 6 * 6 * NH_), 256, 0, stream>>>(qkvb, attnb);

    // 3) out = attn @ proj_w.T + proj_b.  A bf16 reg-staged, B fp32 reg-staged.
    //    64x64, KTILE=128 -> 8x72 = 576 blocks
    gemm_bt<64, 64, 2, 2, 128, bf16_t, float, float>
        <<<dim3(C_ / 64, ROWS_ / 64), 256, 0, stream>>>(
        attnb, proj_w, proj_b, out, ROWS_, C_, C_, 1.0f, 0);
}